// Round 3
// baseline (1211.255 us; speedup 1.0000x reference)
//
#include <hip/hip_runtime.h>

#define NH 8
#define DH 32
#define ROWS 128          // tokens per block (16 batches x 8 tokens)
#define SLD 36            // q/k/v slab leading dim (8B-aligned rows, bank stagger)

typedef __attribute__((ext_vector_type(8))) short bf16x8;
typedef __attribute__((ext_vector_type(4))) float f32x4;

__device__ __forceinline__ unsigned short f2bf(float f) {
  // round-to-nearest-even bf16 (finite inputs only)
  unsigned u = __float_as_uint(f);
  u = (u + 0x7fffu + ((u >> 16) & 1u)) >> 16;
  return (unsigned short)u;
}

// 8 consecutive bf16 (8B-aligned) -> 8 fp32
__device__ __forceinline__ void ld_bf8(const unsigned short* p, float* f) {
  const uint2 a = *(const uint2*)(p);
  const uint2 b = *(const uint2*)(p + 4);
  f[0] = __uint_as_float(a.x << 16); f[1] = __uint_as_float(a.x & 0xffff0000u);
  f[2] = __uint_as_float(a.y << 16); f[3] = __uint_as_float(a.y & 0xffff0000u);
  f[4] = __uint_as_float(b.x << 16); f[5] = __uint_as_float(b.x & 0xffff0000u);
  f[6] = __uint_as_float(b.y << 16); f[7] = __uint_as_float(b.y & 0xffff0000u);
}

// ---------------- prep: weights -> MFMA-fragment order (bf16), gather bias ----------------
// Fragment layout: lane (quad*16+l15) of fragment (h,t,kk) holds W[k=kk*32+quad*8+e][n],
//   n = (t>>1)*256 + h*32 + (t&1)*16 + l15  (wqkv);  n = p*64 + nt*16 + l15 (wout).
// A wave's B-load is then 64 lanes x 16B = 1KB fully contiguous.
// grid 65: blocks 0..47 = wqkv 64x64 tiles, 48..63 = wout tiles, 64 = bias
__global__ void prep_kernel(const float* __restrict__ wqkv, const float* __restrict__ wout,
                            const float* __restrict__ table, const int* __restrict__ relidx,
                            unsigned short* __restrict__ wqkvF, unsigned short* __restrict__ woutF,
                            float* __restrict__ biasM) {
  __shared__ float T[64][65];
  const int b = blockIdx.x, tid = threadIdx.x;
  if (b == 64) {
    for (int e = tid; e < 512; e += 256) {
      const int hh = e >> 6, ij = e & 63;
      biasM[e] = table[relidx[ij] * NH + hh];   // biasM[h][i*8+j]
    }
    return;
  }
  const float* src; unsigned short* dst; int N, k0, n0; bool isqkv;
  if (b < 48) { src = wqkv; dst = wqkvF; N = 768; k0 = (b / 12) * 64; n0 = (b % 12) * 64; isqkv = true; }
  else { const int bb = b - 48; src = wout; dst = woutF; N = 256; k0 = (bb >> 2) * 64; n0 = (bb & 3) * 64; isqkv = false; }
  const int c = tid & 63, rb = (tid >> 6) * 16;
  #pragma unroll
  for (int p = 0; p < 16; ++p)
    T[c][rb + p] = src[(size_t)(k0 + rb + p) * N + n0 + c];   // coalesced read; T[n_loc][k_loc]
  __syncthreads();
  #pragma unroll
  for (int it = 0; it < 2; ++it) {
    const int chunk = tid * 2 + it;           // 0..511 : (n_loc 0..63) x (k-chunk 0..7)
    const int n_loc = chunk >> 3, kc = chunk & 7;
    const int n = n0 + n_loc, k = k0 + kc * 8;
    const int l15 = n & 15, quad = (k >> 3) & 3, kk = k >> 5;
    // fold q-scale (32^-0.5) into the q section of wqkv
    const float sc = (isqkv && n < 256) ? 0.17677669529663687f : 1.f;
    union { unsigned short e[8]; uint4 q; } u;
    #pragma unroll
    for (int e = 0; e < 8; ++e) u.e[e] = f2bf(T[n_loc][kc * 8 + e] * sc);
    size_t faddr;
    if (isqkv) {
      const int sec = n >> 8, hh = (n >> 5) & 7, tu = (n >> 4) & 1;
      faddr = (size_t)((((hh * 6 + sec * 2 + tu) * 8 + kk) * 64 + quad * 16 + l15) * 8);
    } else {
      const int pp = n >> 6, nt = (n >> 4) & 3;
      faddr = (size_t)((((pp * 4 + nt) * 8 + kk) * 64 + quad * 16 + l15) * 8);
    }
    *(uint4*)&dst[faddr] = u.q;
  }
}

// ---------------- fused main kernel ----------------
// LDS: 3*9216 slabs + 2048 bias = 29696 B ; __launch_bounds__(256,3) -> 3 blocks/CU
__global__ __launch_bounds__(256, 3)
void attn_main(const float* __restrict__ x,
               const float* __restrict__ ln_w,
               const float* __restrict__ ln_b,
               const unsigned short* __restrict__ wqkvF,
               const unsigned short* __restrict__ woutF,
               const float* __restrict__ biasM,
               float* __restrict__ out) {
  __shared__ unsigned short s_q[ROWS * SLD];
  __shared__ unsigned short s_k[ROWS * SLD];
  __shared__ unsigned short s_v[ROWS * SLD];
  __shared__ float s_bias[NH * 64];

  const int tid  = threadIdx.x;
  const int w    = tid >> 6;        // wave 0..3
  const int lane = tid & 63;
  const int l15  = lane & 15;
  const int l7   = lane & 7;
  const int quad = lane >> 4;
  const int row0 = blockIdx.x * ROWS;
  const int fl8  = lane * 8;        // this lane's 16B slot within a 1KB fragment

  for (int e = tid; e < 512; e += 256) s_bias[e] = biasM[e];

  // ---- LayerNorm directly into register-resident A-fragments ----
  // lane holds A[m=l15][k=quad*8+j] for kstep kk; wave w owns m-tiles {2w, 2w+1}
  bf16x8 afrag[2][8];
  #pragma unroll
  for (int mt = 0; mt < 2; ++mt) {
    const int lrow = (2 * w + mt) * 16 + l15;
    const float* xr = x + (size_t)(row0 + lrow) * 256;
    float4 xv[16];
    float sum = 0.f, ss = 0.f;
    #pragma unroll
    for (int kk = 0; kk < 8; ++kk) {
      #pragma unroll
      for (int i = 0; i < 2; ++i) {
        const float4 v = *(const float4*)(xr + kk * 32 + quad * 8 + i * 4);
        xv[kk * 2 + i] = v;
        sum += v.x + v.y + v.z + v.w;
        ss  += v.x * v.x + v.y * v.y + v.z * v.z + v.w * v.w;
      }
    }
    sum += __shfl_xor(sum, 16); ss += __shfl_xor(ss, 16);
    sum += __shfl_xor(sum, 32); ss += __shfl_xor(ss, 32);
    const float mean = sum * (1.f / 256.f);
    const float var  = ss * (1.f / 256.f) - mean * mean;
    const float rstd = rsqrtf(var + 1e-5f);
    #pragma unroll
    for (int kk = 0; kk < 8; ++kk) {
      union { bf16x8 v; unsigned short e[8]; } pk;
      #pragma unroll
      for (int i = 0; i < 2; ++i) {
        const float4 g   = *(const float4*)(ln_w + kk * 32 + quad * 8 + i * 4);
        const float4 bta = *(const float4*)(ln_b + kk * 32 + quad * 8 + i * 4);
        const float4 v = xv[kk * 2 + i];
        pk.e[i * 4 + 0] = f2bf((v.x - mean) * rstd * g.x + bta.x);
        pk.e[i * 4 + 1] = f2bf((v.y - mean) * rstd * g.y + bta.y);
        pk.e[i * 4 + 2] = f2bf((v.z - mean) * rstd * g.z + bta.z);
        pk.e[i * 4 + 3] = f2bf((v.w - mean) * rstd * g.w + bta.w);
      }
      afrag[mt][kk] = pk.v;
    }
  }

  // attention output in MFMA-A-fragment layout: ao[mt][h] = dims quad*8..+8 of row (2w+mt)*16+l15
  bf16x8 ao[2][NH];

  #pragma unroll
  for (int h = 0; h < NH; ++h) {
    // ---- QKV MFMA for head h: B-fragments straight from L1/L2 (1KB coalesced per load) ----
    const f32x4 fz = {0.f, 0.f, 0.f, 0.f};
    #pragma unroll
    for (int s = 0; s < 3; ++s) {       // 0=q 1=k 2=v  (16 n-cols each, 2 sub-tiles)
      f32x4 acc[2][2];
      acc[0][0] = fz; acc[0][1] = fz; acc[1][0] = fz; acc[1][1] = fz;
      #pragma unroll
      for (int kk = 0; kk < 8; ++kk) {
        const bf16x8 a0 = afrag[0][kk];
        const bf16x8 a1 = afrag[1][kk];
        #pragma unroll
        for (int u = 0; u < 2; ++u) {
          const bf16x8 bfr = *(const bf16x8*)&wqkvF[(size_t)(((h * 6 + s * 2 + u) * 8 + kk) * 512) + fl8];
          acc[0][u] = __builtin_amdgcn_mfma_f32_16x16x32_bf16(a0, bfr, acc[0][u], 0, 0, 0);
          acc[1][u] = __builtin_amdgcn_mfma_f32_16x16x32_bf16(a1, bfr, acc[1][u], 0, 0, 0);
        }
      }
      // C layout: col=l15, row=quad*4+r -> scatter section s (q-scale pre-folded in weights)
      unsigned short* slab = (s == 0) ? s_q : (s == 1) ? s_k : s_v;
      #pragma unroll
      for (int mt = 0; mt < 2; ++mt)
        #pragma unroll
        for (int u = 0; u < 2; ++u)
          #pragma unroll
          for (int r = 0; r < 4; ++r) {
            const int row = (2 * w + mt) * 16 + quad * 4 + r;
            slab[row * SLD + u * 16 + l15] = f2bf(acc[mt][u][r]);
          }
    }
    __syncthreads();   // slabs (and, on h==0, s_bias) visible

    // ---- attention: thread owns rows (2w+mt)*16+l15, dims quad*8..+8 ----
    const float4 bb0 = *(const float4*)&s_bias[h * 64 + l7 * 8];
    const float4 bb1 = *(const float4*)&s_bias[h * 64 + l7 * 8 + 4];
    #pragma unroll
    for (int mt = 0; mt < 2; ++mt) {
      const int i  = (2 * w + mt) * 16 + l15;
      const int bl = i >> 3;
      const int kbase = (bl * 8) * SLD + quad * 8;
      float q8[8];
      ld_bf8(&s_q[i * SLD + quad * 8], q8);
      float sc[8];
      #pragma unroll
      for (int j = 0; j < 8; ++j) {
        float k8[8];
        ld_bf8(&s_k[kbase + j * SLD], k8);
        sc[j] = q8[0]*k8[0] + q8[1]*k8[1] + q8[2]*k8[2] + q8[3]*k8[3]
              + q8[4]*k8[4] + q8[5]*k8[5] + q8[6]*k8[6] + q8[7]*k8[7];
      }
      // reduce partial dots across the 4 quads holding this row
      #pragma unroll
      for (int j = 0; j < 8; ++j) sc[j] += __shfl_xor(sc[j], 16);
      #pragma unroll
      for (int j = 0; j < 8; ++j) sc[j] += __shfl_xor(sc[j], 32);
      sc[0] += bb0.x; sc[1] += bb0.y; sc[2] += bb0.z; sc[3] += bb0.w;
      sc[4] += bb1.x; sc[5] += bb1.y; sc[6] += bb1.z; sc[7] += bb1.w;
      float mx = fmaxf(fmaxf(fmaxf(sc[0], sc[1]), fmaxf(sc[2], sc[3])),
                       fmaxf(fmaxf(sc[4], sc[5]), fmaxf(sc[6], sc[7])));
      float ex[8], sumw = 0.f;
      #pragma unroll
      for (int j = 0; j < 8; ++j) { ex[j] = __expf(sc[j] - mx); sumw += ex[j]; }
      const float inv = 1.f / sumw;
      float o8[8] = {0.f, 0.f, 0.f, 0.f, 0.f, 0.f, 0.f, 0.f};
      #pragma unroll
      for (int j = 0; j < 8; ++j) {
        const float p = ex[j] * inv;
        float v8[8];
        ld_bf8(&s_v[kbase + j * SLD], v8);
        o8[0] += p * v8[0]; o8[1] += p * v8[1]; o8[2] += p * v8[2]; o8[3] += p * v8[3];
        o8[4] += p * v8[4]; o8[5] += p * v8[5]; o8[6] += p * v8[6]; o8[7] += p * v8[7];
      }
      union { bf16x8 v; unsigned u[4]; } pk;
      #pragma unroll
      for (int d2 = 0; d2 < 4; ++d2)
        pk.u[d2] = (unsigned)f2bf(o8[2 * d2]) | ((unsigned)f2bf(o8[2 * d2 + 1]) << 16);
      ao[mt][h] = pk.v;
    }
    __syncthreads();   // slab reads done before next head's scatter
  }

  // ---- output projection: out = ao @ w_out, A from registers, B from L1/L2 ----
  for (int p = 0; p < 4; ++p) {
    const f32x4 fz = {0.f, 0.f, 0.f, 0.f};
    f32x4 oacc[2][4];
    #pragma unroll
    for (int mt = 0; mt < 2; ++mt)
      #pragma unroll
      for (int nt = 0; nt < 4; ++nt) oacc[mt][nt] = fz;

    #pragma unroll
    for (int kk = 0; kk < 8; ++kk) {     // kstep == head
      const bf16x8 a0 = ao[0][kk];
      const bf16x8 a1 = ao[1][kk];
      #pragma unroll
      for (int nt = 0; nt < 4; ++nt) {
        const bf16x8 bfr = *(const bf16x8*)&woutF[(size_t)(((p * 4 + nt) * 8 + kk) * 512) + fl8];
        oacc[0][nt] = __builtin_amdgcn_mfma_f32_16x16x32_bf16(a0, bfr, oacc[0][nt], 0, 0, 0);
        oacc[1][nt] = __builtin_amdgcn_mfma_f32_16x16x32_bf16(a1, bfr, oacc[1][nt], 0, 0, 0);
      }
    }
    #pragma unroll
    for (int mt = 0; mt < 2; ++mt)
      #pragma unroll
      for (int nt = 0; nt < 4; ++nt)
        #pragma unroll
        for (int r = 0; r < 4; ++r) {
          const int grow = row0 + (2 * w + mt) * 16 + quad * 4 + r;
          out[(size_t)grow * 256 + p * 64 + nt * 16 + l15] = oacc[mt][nt][r];
        }
  }
}

extern "C" void kernel_launch(void* const* d_in, const int* in_sizes, int n_in,
                              void* d_out, int out_size, void* d_ws, size_t ws_size,
                              hipStream_t stream) {
  const float* x      = (const float*)d_in[0];
  const float* ln_w   = (const float*)d_in[1];
  const float* ln_b   = (const float*)d_in[2];
  const float* wqkv   = (const float*)d_in[3];
  const float* wout   = (const float*)d_in[4];
  const float* table  = (const float*)d_in[5];
  const int*   relidx = (const int*)d_in[6];
  float* out = (float*)d_out;

  unsigned short* wqkvF = (unsigned short*)d_ws;        // 768*256 bf16 (fragment order)
  unsigned short* woutF = wqkvF + 768 * 256;            // 256*256 bf16 (fragment order)
  float* biasM = (float*)(woutF + 256 * 256);           // 8*64 fp32

  prep_kernel<<<65, 256, 0, stream>>>(wqkv, wout, table, relidx, wqkvF, woutF, biasM);
  attn_main<<<2048, 256, 0, stream>>>(x, ln_w, ln_b, wqkvF, woutF, biasM, out);
}

// Round 4
// 601.768 us; speedup vs baseline: 2.0128x; 2.0128x over previous
//
#include <hip/hip_runtime.h>

#define NH 8
#define DH 32
#define ROWS 128          // tokens per block (16 batches x 8 tokens)
#define SLD 36            // q/k slab leading dim (bank stagger, 16B-friendly)
#define VTLD 20           // vT slab leading dim (8B aligned rows, bank stagger)

typedef __attribute__((ext_vector_type(8))) short bf16x8;
typedef __attribute__((ext_vector_type(4))) short bf16x4;
typedef __attribute__((ext_vector_type(4))) float f32x4;

__device__ __forceinline__ unsigned short f2bf(float f) {
  // round-to-nearest-even bf16 (finite inputs only)
  unsigned u = __float_as_uint(f);
  u = (u + 0x7fffu + ((u >> 16) & 1u)) >> 16;
  return (unsigned short)u;
}

// async 16B/lane global->LDS (wave-uniform LDS base, per-lane global addr)
__device__ __forceinline__ void gload16(const void* g, void* l) {
  __builtin_amdgcn_global_load_lds((const __attribute__((address_space(1))) void*)g,
                                   (__attribute__((address_space(3))) void*)l, 16, 0, 0);
}

// ---------------- prep: weights -> MFMA-fragment order (bf16), gather bias ----------------
// wqkvF: x32 B-fragments, frag = (h*6 + sec*2 + tu)*8 + kk (1KB each, 48KB/head).
//   lane (quad*16+l15) of a frag holds W[k=kk*32+quad*8+e][n=sec*256+h*32+tu*16+l15], e=0..7.
// woutF: x16 B-fragments for the out-proj, frag flat = (ntg>>2)*64 + c*4 + (ntg&3) (512B each),
//   lane holds W[k=c*16+quad*4+j][n=ntg*16+l15], j=0..3.  Chunk p = flat [p*64, p*64+64) = 32KB.
__global__ void prep_kernel(const float* __restrict__ wqkv, const float* __restrict__ wout,
                            const float* __restrict__ table, const int* __restrict__ relidx,
                            unsigned short* __restrict__ wqkvF, unsigned short* __restrict__ woutF,
                            float* __restrict__ biasM) {
  __shared__ float T[64][65];
  const int b = blockIdx.x, tid = threadIdx.x;
  if (b == 64) {
    for (int e = tid; e < 512; e += 256) {
      const int hh = e >> 6, ij = e & 63;
      biasM[e] = table[relidx[ij] * NH + hh];   // biasM[h][i*8+j]
    }
    return;
  }
  const float* src; int N, k0, n0; bool isqkv;
  if (b < 48) { src = wqkv; N = 768; k0 = (b / 12) * 64; n0 = (b % 12) * 64; isqkv = true; }
  else { const int bb = b - 48; src = wout; N = 256; k0 = (bb >> 2) * 64; n0 = (bb & 3) * 64; isqkv = false; }
  const int c = tid & 63, rb = (tid >> 6) * 16;
  #pragma unroll
  for (int p = 0; p < 16; ++p)
    T[c][rb + p] = src[(size_t)(k0 + rb + p) * N + n0 + c];   // coalesced read; T[n_loc][k_loc]
  __syncthreads();
  #pragma unroll
  for (int it = 0; it < 2; ++it) {
    const int chunk = tid * 2 + it;           // 0..511 : (n_loc 0..63) x (k-chunk 0..7)
    const int n_loc = chunk >> 3, kc = chunk & 7;
    const int n = n0 + n_loc, k = k0 + kc * 8;
    if (isqkv) {
      const int l15 = n & 15, quad = (k >> 3) & 3, kk = k >> 5;
      // fold q-scale (32^-0.5) into the q section of wqkv
      const float sc = (n < 256) ? 0.17677669529663687f : 1.f;
      union { unsigned short e[8]; uint4 q; } u;
      #pragma unroll
      for (int e = 0; e < 8; ++e) u.e[e] = f2bf(T[n_loc][kc * 8 + e] * sc);
      const int sec = n >> 8, hh = (n >> 5) & 7, tu = (n >> 4) & 1;
      const size_t faddr = (size_t)((((hh * 6 + sec * 2 + tu) * 8 + kk) * 64 + quad * 16 + l15) * 8);
      *(uint4*)&wqkvF[faddr] = u.q;
    } else {
      const int ntg = n >> 4, nl = n & 15;
      #pragma unroll
      for (int g = 0; g < 2; ++g) {
        const int k4 = k + g * 4;
        const int cc = k4 >> 4, qd = (k4 >> 2) & 3;
        const int flat = (ntg >> 2) * 64 + cc * 4 + (ntg & 3);
        ushort4 u4;
        u4.x = f2bf(T[n_loc][kc * 8 + g * 4 + 0]);
        u4.y = f2bf(T[n_loc][kc * 8 + g * 4 + 1]);
        u4.z = f2bf(T[n_loc][kc * 8 + g * 4 + 2]);
        u4.w = f2bf(T[n_loc][kc * 8 + g * 4 + 3]);
        *(ushort4*)&woutF[(size_t)((flat * 64 + qd * 16 + nl) * 4)] = u4;
      }
    }
  }
}

// ---------------- fused main kernel ----------------
// LDS: stage 49152 + q 9216 + k 9216 + vT 10240 + bias 2048 = 79872 B -> 2 blocks/CU
__global__ __launch_bounds__(256, 2)
void attn_main(const float* __restrict__ x,
               const float* __restrict__ ln_w,
               const float* __restrict__ ln_b,
               const unsigned short* __restrict__ wqkvF,
               const unsigned short* __restrict__ woutF,
               const float* __restrict__ biasM,
               float* __restrict__ out) {
  __shared__ unsigned short s_stage[96 * 256];       // linear fragment buffer (48KB)
  __shared__ unsigned short s_q[ROWS * SLD];
  __shared__ unsigned short s_k[ROWS * SLD];
  __shared__ unsigned short s_vT[8 * 32 * VTLD];     // [tile][d 0..31][tok 0..15] transposed V
  __shared__ float s_bias[NH * 64];

  const int tid  = threadIdx.x;
  const int w    = tid >> 6;        // wave 0..3
  const int lane = tid & 63;
  const int l15  = lane & 15;
  const int quad = lane >> 4;
  const int row0 = blockIdx.x * ROWS;

  // linear async stagers: wave w copies its 1KB chunks, lane i -> bytes [i*16, i*16+16)
  auto stage_qkv = [&](int hh) {     // 48 x 1KB fragments of head hh
    #pragma unroll
    for (int it = 0; it < 12; ++it)
      gload16(wqkvF + (size_t)(hh * 48 + w * 12 + it) * 512 + lane * 8,
              &s_stage[(w * 12 + it) * 512]);
  };
  auto stage_out = [&](int pp) {     // 32KB chunk pp of woutF (64 x 512B fragments)
    #pragma unroll
    for (int it = 0; it < 8; ++it)
      gload16(woutF + (size_t)pp * 16384 + (w * 8 + it) * 512 + lane * 8,
              &s_stage[(w * 8 + it) * 512]);
  };

  stage_qkv(0);   // in flight under LayerNorm
  for (int e = tid; e < 512; e += 256) s_bias[e] = biasM[e];

  // ---- LayerNorm directly into register-resident A-fragments ----
  // lane holds A[m=l15][k=quad*8+j] for kstep kk; wave w owns m-tiles {2w, 2w+1}
  bf16x8 afrag[2][8];
  #pragma unroll
  for (int mt = 0; mt < 2; ++mt) {
    const int lrow = (2 * w + mt) * 16 + l15;
    const float* xr = x + (size_t)(row0 + lrow) * 256;
    float4 xv[16];
    float sum = 0.f, ss = 0.f;
    #pragma unroll
    for (int kk = 0; kk < 8; ++kk) {
      #pragma unroll
      for (int i = 0; i < 2; ++i) {
        const float4 v = *(const float4*)(xr + kk * 32 + quad * 8 + i * 4);
        xv[kk * 2 + i] = v;
        sum += v.x + v.y + v.z + v.w;
        ss  += v.x * v.x + v.y * v.y + v.z * v.z + v.w * v.w;
      }
    }
    sum += __shfl_xor(sum, 16); ss += __shfl_xor(ss, 16);
    sum += __shfl_xor(sum, 32); ss += __shfl_xor(ss, 32);
    const float mean = sum * (1.f / 256.f);
    const float var  = ss * (1.f / 256.f) - mean * mean;
    const float rstd = rsqrtf(var + 1e-5f);
    #pragma unroll
    for (int kk = 0; kk < 8; ++kk) {
      union { bf16x8 v; unsigned short e[8]; } pk;
      #pragma unroll
      for (int i = 0; i < 2; ++i) {
        const float4 g   = *(const float4*)(ln_w + kk * 32 + quad * 8 + i * 4);
        const float4 bta = *(const float4*)(ln_b + kk * 32 + quad * 8 + i * 4);
        const float4 v = xv[kk * 2 + i];
        pk.e[i * 4 + 0] = f2bf((v.x - mean) * rstd * g.x + bta.x);
        pk.e[i * 4 + 1] = f2bf((v.y - mean) * rstd * g.y + bta.y);
        pk.e[i * 4 + 2] = f2bf((v.z - mean) * rstd * g.z + bta.z);
        pk.e[i * 4 + 3] = f2bf((v.w - mean) * rstd * g.w + bta.w);
      }
      afrag[mt][kk] = pk.v;
    }
  }
  __syncthreads();   // stage(0) landed (vmcnt drained at barrier) + bias visible

  // attention output as x16 A-fragments for the out-proj: ao[mt][c=2h+u], lane l15 = token,
  // elements j = d_local quad*4+j of k-chunk c. Accumulated head by head.
  bf16x4 ao[2][16];
  const f32x4 fz = {0.f, 0.f, 0.f, 0.f};

  #pragma unroll
  for (int h = 0; h < NH; ++h) {
    // ---- QKV MFMA for head h (x32 B-fragments from linear s_stage) ----
    f32x4 acc[2][6];
    #pragma unroll
    for (int mt = 0; mt < 2; ++mt)
      #pragma unroll
      for (int t = 0; t < 6; ++t) acc[mt][t] = fz;
    #pragma unroll
    for (int kk = 0; kk < 8; ++kk) {
      const bf16x8 a0 = afrag[0][kk];
      const bf16x8 a1 = afrag[1][kk];
      #pragma unroll
      for (int t = 0; t < 6; ++t) {
        const bf16x8 bfr = *(const bf16x8*)&s_stage[(t * 8 + kk) * 512 + lane * 8];
        acc[0][t] = __builtin_amdgcn_mfma_f32_16x16x32_bf16(a0, bfr, acc[0][t], 0, 0, 0);
        acc[1][t] = __builtin_amdgcn_mfma_f32_16x16x32_bf16(a1, bfr, acc[1][t], 0, 0, 0);
      }
    }
    __syncthreads();   // all waves done reading s_stage(h)
    if (h < NH - 1) stage_qkv(h + 1); else stage_out(0);   // DMA hides under scatter+attn

    // ---- scatter: q,k row-major; V transposed into s_vT ----
    // C layout: col=l15 (n within 16-col section), row=quad*4+r (token within tile)
    #pragma unroll
    for (int mt = 0; mt < 2; ++mt) {
      const int rowb = (2 * w + mt) * 16 + quad * 4;
      #pragma unroll
      for (int u = 0; u < 2; ++u) {
        #pragma unroll
        for (int r = 0; r < 4; ++r) {
          s_q[(rowb + r) * SLD + u * 16 + l15] = f2bf(acc[mt][u][r]);
          s_k[(rowb + r) * SLD + u * 16 + l15] = f2bf(acc[mt][2 + u][r]);
        }
        ushort4 v4;
        v4.x = f2bf(acc[mt][4 + u][0]); v4.y = f2bf(acc[mt][4 + u][1]);
        v4.z = f2bf(acc[mt][4 + u][2]); v4.w = f2bf(acc[mt][4 + u][3]);
        *(ushort4*)&s_vT[((2 * w + mt) * 32 + u * 16 + l15) * VTLD + quad * 4] = v4;
      }
    }
    // slabs are wave-private (producer wave == consumer wave) -> no barrier needed here

    // ---- attention, MFMA form. S^T = mfma32(A=K,B=Q): lane l15=q, regs r = k=quad*4+r ----
    const float4 bb = *(const float4*)&s_bias[h * 64 + (l15 & 7) * 8 + (quad & 1) * 4];
    const bool valid = (quad >> 1) == (l15 >> 3);   // block-diagonal mask
    #pragma unroll
    for (int mt = 0; mt < 2; ++mt) {
      const int tb = (2 * w + mt) * 16;
      const bf16x8 kf = *(const bf16x8*)&s_k[(tb + l15) * SLD + quad * 8];
      const bf16x8 qf = *(const bf16x8*)&s_q[(tb + l15) * SLD + quad * 8];
      const f32x4 st = __builtin_amdgcn_mfma_f32_16x16x32_bf16(kf, qf, fz, 0, 0, 0);
      float sc0 = valid ? st[0] + bb.x : -3.0e38f;
      float sc1 = valid ? st[1] + bb.y : -3.0e38f;
      float sc2 = valid ? st[2] + bb.z : -3.0e38f;
      float sc3 = valid ? st[3] + bb.w : -3.0e38f;
      float mx = fmaxf(fmaxf(sc0, sc1), fmaxf(sc2, sc3));
      mx = fmaxf(mx, __shfl_xor(mx, 16));
      mx = fmaxf(mx, __shfl_xor(mx, 32));
      const float e0 = __expf(sc0 - mx), e1 = __expf(sc1 - mx);
      const float e2 = __expf(sc2 - mx), e3 = __expf(sc3 - mx);
      float s4 = e0 + e1 + e2 + e3;
      s4 += __shfl_xor(s4, 16);
      s4 += __shfl_xor(s4, 32);
      const float inv = 1.f / s4;     // applied in fp32 after PV (keeps P precision)
      union { bf16x4 v; unsigned short e[4]; } pf;
      pf.e[0] = f2bf(e0); pf.e[1] = f2bf(e1); pf.e[2] = f2bf(e2); pf.e[3] = f2bf(e3);
      // O^T = mfma16(A=V^T, B=P^T): lane l15=q, regs r = d_local quad*4+r  (per u half)
      #pragma unroll
      for (int u = 0; u < 2; ++u) {
        const bf16x4 vf = *(const bf16x4*)&s_vT[((2 * w + mt) * 32 + u * 16 + l15) * VTLD + quad * 4];
        const f32x4 ot = __builtin_amdgcn_mfma_f32_16x16x16bf16_1k(vf, pf.v, fz, 0, 0, 0);
        union { bf16x4 v; unsigned short e[4]; } po;
        po.e[0] = f2bf(ot[0] * inv); po.e[1] = f2bf(ot[1] * inv);
        po.e[2] = f2bf(ot[2] * inv); po.e[3] = f2bf(ot[3] * inv);
        ao[mt][2 * h + u] = po.v;
      }
    }
    __syncthreads();   // next-head stage landed (vmcnt drains at barrier), all waves aligned
  }

  // ---- output projection: out = ao @ w_out via x16 MFMAs, B staged in 32KB chunks ----
  for (int p = 0; p < 4; ++p) {
    f32x4 oacc[2][4];
    #pragma unroll
    for (int mt = 0; mt < 2; ++mt)
      #pragma unroll
      for (int nt = 0; nt < 4; ++nt) oacc[mt][nt] = fz;

    #pragma unroll
    for (int c = 0; c < 16; ++c) {
      const bf16x4 a0 = ao[0][c];
      const bf16x4 a1 = ao[1][c];
      #pragma unroll
      for (int nt = 0; nt < 4; ++nt) {
        const bf16x4 bfr = *(const bf16x4*)&s_stage[(c * 4 + nt) * 256 + lane * 4];
        oacc[0][nt] = __builtin_amdgcn_mfma_f32_16x16x16bf16_1k(a0, bfr, oacc[0][nt], 0, 0, 0);
        oacc[1][nt] = __builtin_amdgcn_mfma_f32_16x16x16bf16_1k(a1, bfr, oacc[1][nt], 0, 0, 0);
      }
    }
    if (p < 3) {
      __syncthreads();      // all s_stage reads of chunk p done
      stage_out(p + 1);     // in flight under the C-write below
    }
    #pragma unroll
    for (int mt = 0; mt < 2; ++mt)
      #pragma unroll
      for (int nt = 0; nt < 4; ++nt)
        #pragma unroll
        for (int r = 0; r < 4; ++r) {
          const int grow = row0 + (2 * w + mt) * 16 + quad * 4 + r;
          out[(size_t)grow * 256 + p * 64 + nt * 16 + l15] = oacc[mt][nt][r];
        }
    if (p < 3) __syncthreads();   // chunk p+1 landed
  }
}

extern "C" void kernel_launch(void* const* d_in, const int* in_sizes, int n_in,
                              void* d_out, int out_size, void* d_ws, size_t ws_size,
                              hipStream_t stream) {
  const float* x      = (const float*)d_in[0];
  const float* ln_w   = (const float*)d_in[1];
  const float* ln_b   = (const float*)d_in[2];
  const float* wqkv   = (const float*)d_in[3];
  const float* wout   = (const float*)d_in[4];
  const float* table  = (const float*)d_in[5];
  const int*   relidx = (const int*)d_in[6];
  float* out = (float*)d_out;

  unsigned short* wqkvF = (unsigned short*)d_ws;        // 768*256 bf16 (x32 fragment order)
  unsigned short* woutF = wqkvF + 768 * 256;            // 256*256 bf16 (x16 fragment order)
  float* biasM = (float*)(woutF + 256 * 256);           // 8*64 fp32

  prep_kernel<<<65, 256, 0, stream>>>(wqkv, wout, table, relidx, wqkvF, woutF, biasM);
  attn_main<<<2048, 256, 0, stream>>>(x, ln_w, ln_b, wqkvF, woutF, biasM, out);
}